// Round 1
// baseline (2810.616 us; speedup 1.0000x reference)
//
#include <hip/hip_runtime.h>

#define N_NODES 65536
#define N_EDGES 1048576
#define E_TOTAL (N_EDGES + N_NODES)
#define VOCAB 50000
#define HIDDEN 256
#define NUM_GRAPHS 64
#define NEG_SLOPE 0.2f
#define SM_EPS 1e-16f

// ---------------- gather: x = emb[nodes] ----------------
__global__ __launch_bounds__(256) void gather_kernel(const int* __restrict__ nodes,
    const float* __restrict__ emb, float* __restrict__ x) {
    int i = blockIdx.x;
    int t = threadIdx.x;
    x[(size_t)i * HIDDEN + t] = emb[(size_t)nodes[i] * HIDDEN + t];
}

// ---------------- CSR build (by dst) ----------------
__global__ __launch_bounds__(256) void hist_kernel(const int* __restrict__ ei, int* __restrict__ counts) {
    int e = blockIdx.x * 256 + threadIdx.x;
    if (e >= E_TOTAL) return;
    int dst = (e < N_EDGES) ? ei[N_EDGES + e] : (e - N_EDGES);
    atomicAdd(&counts[dst], 1);
}

__global__ __launch_bounds__(1024) void scan_kernel(const int* __restrict__ counts,
    int* __restrict__ row_ptr, int* __restrict__ cursor) {
    __shared__ int sp[1024];
    int t = threadIdx.x;
    int base = t * 64;
    int s = 0;
    for (int i = 0; i < 64; i++) s += counts[base + i];
    sp[t] = s;
    __syncthreads();
    // Hillis-Steele inclusive scan over 1024 partials
    for (int d = 1; d < 1024; d <<= 1) {
        int v = (t >= d) ? sp[t - d] : 0;
        __syncthreads();
        sp[t] += v;
        __syncthreads();
    }
    int run = sp[t] - s;  // exclusive offset for this thread's chunk
    for (int i = 0; i < 64; i++) {
        int c = counts[base + i];
        row_ptr[base + i] = run;
        cursor[base + i] = run;
        run += c;
    }
    if (t == 1023) row_ptr[N_NODES] = run;
}

__global__ __launch_bounds__(256) void scatter_kernel(const int* __restrict__ ei,
    int* __restrict__ cursor, int* __restrict__ src_sorted) {
    int e = blockIdx.x * 256 + threadIdx.x;
    if (e >= E_TOTAL) return;
    int src, dst;
    if (e < N_EDGES) { src = ei[e]; dst = ei[N_EDGES + e]; }
    else             { src = dst = e - N_EDGES; }
    int pos = atomicAdd(&cursor[dst], 1);
    src_sorted[pos] = src;
}

// ---------------- fp32 GEMM: C[N,256] = A[N,256] @ W[256,256] (+bias) ----------------
// Tile 64x128, BK=16, 256 threads, 4x8 micro-tile (two 4x4 column halves).
__global__ __launch_bounds__(256) void gemm_kernel(const float* __restrict__ A,
    const float* __restrict__ W, const float* __restrict__ bias,
    float* __restrict__ C) {
    __shared__ float As[16][64 + 4];
    __shared__ float Bs[16][128 + 8];
    int tid = threadIdx.x;
    int tx = tid & 15;
    int ty = tid >> 4;
    int m0 = blockIdx.x * 64;
    int n0 = blockIdx.y * 128;
    int arow = tid >> 2;
    int akc = (tid & 3) << 2;
    int brow = ty;          // 0..15
    int bcol = tx << 2;     // 0..60

    float acc0[4][4] = {{0.f}};
    float acc1[4][4] = {{0.f}};

    for (int k0 = 0; k0 < HIDDEN; k0 += 16) {
        float4 av  = *(const float4*)(A + (size_t)(m0 + arow) * HIDDEN + k0 + akc);
        float4 bv0 = *(const float4*)(W + (size_t)(k0 + brow) * HIDDEN + n0 + bcol);
        float4 bv1 = *(const float4*)(W + (size_t)(k0 + brow) * HIDDEN + n0 + 64 + bcol);
        __syncthreads();
        As[akc + 0][arow] = av.x;
        As[akc + 1][arow] = av.y;
        As[akc + 2][arow] = av.z;
        As[akc + 3][arow] = av.w;
        *(float4*)&Bs[brow][bcol] = bv0;
        *(float4*)&Bs[brow][64 + bcol] = bv1;
        __syncthreads();
        #pragma unroll
        for (int k = 0; k < 16; k++) {
            float4 a  = *(const float4*)&As[k][ty << 2];
            float4 b0 = *(const float4*)&Bs[k][tx << 2];
            float4 b1 = *(const float4*)&Bs[k][64 + (tx << 2)];
            float aa[4] = {a.x, a.y, a.z, a.w};
            float bb0[4] = {b0.x, b0.y, b0.z, b0.w};
            float bb1[4] = {b1.x, b1.y, b1.z, b1.w};
            #pragma unroll
            for (int i = 0; i < 4; i++) {
                #pragma unroll
                for (int j = 0; j < 4; j++) {
                    acc0[i][j] += aa[i] * bb0[j];
                    acc1[i][j] += aa[i] * bb1[j];
                }
            }
        }
    }
    #pragma unroll
    for (int i = 0; i < 4; i++) {
        int row = m0 + (ty << 2) + i;
        int c0 = n0 + (tx << 2);
        int c1 = n0 + 64 + (tx << 2);
        float4 r0 = make_float4(acc0[i][0], acc0[i][1], acc0[i][2], acc0[i][3]);
        float4 r1 = make_float4(acc1[i][0], acc1[i][1], acc1[i][2], acc1[i][3]);
        if (bias != nullptr) {
            r0.x += bias[c0 + 0]; r0.y += bias[c0 + 1]; r0.z += bias[c0 + 2]; r0.w += bias[c0 + 3];
            r1.x += bias[c1 + 0]; r1.y += bias[c1 + 1]; r1.z += bias[c1 + 2]; r1.w += bias[c1 + 3];
        }
        *(float4*)(C + (size_t)row * HIDDEN + c0) = r0;
        *(float4*)(C + (size_t)row * HIDDEN + c1) = r1;
    }
}

// ---------------- per-node attention scalars: es = h@a_src, ed = h@a_dst ----------------
__global__ __launch_bounds__(256) void dots_kernel(const float* __restrict__ h,
    const float* __restrict__ a_s, const float* __restrict__ a_d,
    float* __restrict__ es, float* __restrict__ ed) {
    int gtid = blockIdx.x * 256 + threadIdx.x;
    int node = gtid >> 6;
    int lane = threadIdx.x & 63;
    if (node >= N_NODES) return;
    float4 hv = *(const float4*)(h + (size_t)node * HIDDEN + lane * 4);
    float4 s4 = *(const float4*)(a_s + lane * 4);
    float4 d4 = *(const float4*)(a_d + lane * 4);
    float s = hv.x * s4.x + hv.y * s4.y + hv.z * s4.z + hv.w * s4.w;
    float d = hv.x * d4.x + hv.y * d4.y + hv.z * d4.z + hv.w * d4.w;
    for (int off = 32; off; off >>= 1) {
        s += __shfl_down(s, off);
        d += __shfl_down(d, off);
    }
    if (lane == 0) { es[node] = s; ed[node] = d; }
}

// ---------------- wave-per-dst segment softmax + weighted aggregate ----------------
// g[dst] = relu( sum_e alpha_e * h[src_e] + bg )
__global__ __launch_bounds__(256) void agg_kernel(const float* __restrict__ h,
    const int* __restrict__ row_ptr, const int* __restrict__ src_sorted,
    const float* __restrict__ es, const float* __restrict__ ed,
    const float* __restrict__ bg, float* __restrict__ g) {
    int gtid = blockIdx.x * 256 + threadIdx.x;
    int dst = gtid >> 6;
    int lane = threadIdx.x & 63;
    if (dst >= N_NODES) return;
    int start = row_ptr[dst];
    int end = row_ptr[dst + 1];
    float edd = ed[dst];

    // pass 1a: segment max (lanes parallel over edges)
    float m = -1e30f;
    for (int i = start + lane; i < end; i += 64) {
        float e = es[src_sorted[i]] + edd;
        e = (e > 0.f) ? e : NEG_SLOPE * e;
        m = fmaxf(m, e);
    }
    for (int off = 32; off; off >>= 1) m = fmaxf(m, __shfl_xor(m, off));

    // pass 1b: denom
    float denom = 0.f;
    for (int i = start + lane; i < end; i += 64) {
        float e = es[src_sorted[i]] + edd;
        e = (e > 0.f) ? e : NEG_SLOPE * e;
        denom += __expf(e - m);
    }
    for (int off = 32; off; off >>= 1) denom += __shfl_xor(denom, off);
    float inv = 1.0f / (denom + SM_EPS);

    // pass 2: weighted accumulate; lane owns 4 contiguous columns
    float4 acc = make_float4(0.f, 0.f, 0.f, 0.f);
    for (int i = start; i < end; i++) {
        int s = src_sorted[i];
        float e = es[s] + edd;
        e = (e > 0.f) ? e : NEG_SLOPE * e;
        float alpha = __expf(e - m) * inv;
        float4 hv = *(const float4*)(h + (size_t)s * HIDDEN + lane * 4);
        acc.x += alpha * hv.x;
        acc.y += alpha * hv.y;
        acc.z += alpha * hv.z;
        acc.w += alpha * hv.w;
    }
    float4 b4 = *(const float4*)(bg + lane * 4);
    acc.x = fmaxf(acc.x + b4.x, 0.f);
    acc.y = fmaxf(acc.y + b4.y, 0.f);
    acc.z = fmaxf(acc.z + b4.z, 0.f);
    acc.w = fmaxf(acc.w + b4.w, 0.f);
    *(float4*)(g + (size_t)dst * HIDDEN + lane * 4) = acc;
}

// ---------------- mean pool (transposed accumulator pooledT[k][g]) ----------------
__global__ __launch_bounds__(256) void pool_kernel(const float* __restrict__ x,
    const int* __restrict__ batch, float* __restrict__ pooledT, int* __restrict__ cnt) {
    int idx = blockIdx.x * 256 + threadIdx.x;
    int node = idx >> 6;
    int lane = idx & 63;
    if (node >= N_NODES) return;
    int gph = batch[node];
    float4 v = *(const float4*)(x + (size_t)node * HIDDEN + lane * 4);
    atomicAdd(&pooledT[(lane * 4 + 0) * NUM_GRAPHS + gph], v.x);
    atomicAdd(&pooledT[(lane * 4 + 1) * NUM_GRAPHS + gph], v.y);
    atomicAdd(&pooledT[(lane * 4 + 2) * NUM_GRAPHS + gph], v.z);
    atomicAdd(&pooledT[(lane * 4 + 3) * NUM_GRAPHS + gph], v.w);
    if (lane == 0) atomicAdd(&cnt[gph], 1);
}

__global__ __launch_bounds__(256) void mean_kernel(const float* __restrict__ pooledT,
    const int* __restrict__ cnt, float* __restrict__ meanT) {
    int i = blockIdx.x * 256 + threadIdx.x;  // HIDDEN*NUM_GRAPHS = 16384
    int gph = i & (NUM_GRAPHS - 1);
    float c = (float)max(cnt[gph], 1);
    meanT[i] = pooledT[i] / c;
}

// ---------------- final: out[64,50000] = pooled @ Wout + bout ----------------
// Thread per vocab column; meanT access is wave-uniform -> scalar loads.
__global__ __launch_bounds__(256) void final_kernel(const float* __restrict__ meanT,
    const float* __restrict__ Wout, const float* __restrict__ bout, float* __restrict__ out) {
    int j = blockIdx.x * 256 + threadIdx.x;
    if (j >= VOCAB) return;
    float acc[NUM_GRAPHS];
    #pragma unroll
    for (int g = 0; g < NUM_GRAPHS; g++) acc[g] = 0.f;
    for (int k = 0; k < HIDDEN; k++) {
        float w = Wout[(size_t)k * VOCAB + j];
        #pragma unroll
        for (int g = 0; g < NUM_GRAPHS; g++) acc[g] += meanT[k * NUM_GRAPHS + g] * w;
    }
    float b = bout[j];
    for (int g = 0; g < NUM_GRAPHS; g++) out[(size_t)g * VOCAB + j] = acc[g] + b;
}

extern "C" void kernel_launch(void* const* d_in, const int* in_sizes, int n_in,
                              void* d_out, int out_size, void* d_ws, size_t ws_size,
                              hipStream_t stream) {
    const int*   nodes = (const int*)d_in[0];
    const int*   ei    = (const int*)d_in[1];
    const int*   batch = (const int*)d_in[2];
    const float* emb   = (const float*)d_in[3];
    const float* Wg    = (const float*)d_in[4];
    const float* a_src = (const float*)d_in[5];
    const float* a_dst = (const float*)d_in[6];
    const float* bg    = (const float*)d_in[7];
    const float* Wl    = (const float*)d_in[8];
    const float* bl    = (const float*)d_in[9];
    const float* Wout  = (const float*)d_in[10];
    const float* bout  = (const float*)d_in[11];
    float* out = (float*)d_out;

    char* ws = (char*)d_ws;
    size_t off = 0;
    auto alloc = [&](size_t bytes) -> void* {
        void* p = ws + off;
        off += (bytes + 255) & ~(size_t)255;
        return p;
    };
    float* bufA       = (float*)alloc((size_t)N_NODES * HIDDEN * 4);
    float* bufB       = (float*)alloc((size_t)N_NODES * HIDDEN * 4);
    float* es         = (float*)alloc((size_t)N_NODES * 4);
    float* ed         = (float*)alloc((size_t)N_NODES * 4);
    int*   counts     = (int*)alloc((size_t)N_NODES * 4);
    int*   row_ptr    = (int*)alloc((size_t)(N_NODES + 1) * 4);
    int*   cursor     = (int*)alloc((size_t)N_NODES * 4);
    int*   src_sorted = (int*)alloc((size_t)E_TOTAL * 4);
    float* pooledT    = (float*)alloc((size_t)HIDDEN * NUM_GRAPHS * 4);
    float* meanT      = (float*)alloc((size_t)HIDDEN * NUM_GRAPHS * 4);
    int*   cnt        = (int*)alloc((size_t)NUM_GRAPHS * 4);

    hipMemsetAsync(counts, 0, (size_t)N_NODES * 4, stream);
    hipMemsetAsync(pooledT, 0, (size_t)HIDDEN * NUM_GRAPHS * 4, stream);
    hipMemsetAsync(cnt, 0, (size_t)NUM_GRAPHS * 4, stream);

    gather_kernel<<<N_NODES, 256, 0, stream>>>(nodes, emb, bufA);
    hist_kernel<<<(E_TOTAL + 255) / 256, 256, 0, stream>>>(ei, counts);
    scan_kernel<<<1, 1024, 0, stream>>>(counts, row_ptr, cursor);
    scatter_kernel<<<(E_TOTAL + 255) / 256, 256, 0, stream>>>(ei, cursor, src_sorted);

    float* cur = bufA;  // holds x
    float* oth = bufB;
    for (int l = 0; l < 3; l++) {
        // h = x @ Wg[l]
        gemm_kernel<<<dim3(N_NODES / 64, HIDDEN / 128), 256, 0, stream>>>(
            cur, Wg + (size_t)l * HIDDEN * HIDDEN, nullptr, oth);
        // es/ed
        dots_kernel<<<N_NODES / 4, 256, 0, stream>>>(
            oth, a_src + (size_t)l * HIDDEN, a_dst + (size_t)l * HIDDEN, es, ed);
        // g = relu(aggregate + bg)  (overwrites x, which is dead)
        agg_kernel<<<N_NODES / 4, 256, 0, stream>>>(
            oth, row_ptr, src_sorted, es, ed, bg + (size_t)l * HIDDEN, cur);
        // x_next = g @ Wl[l] + bl  (overwrites h, which is dead)
        gemm_kernel<<<dim3(N_NODES / 64, HIDDEN / 128), 256, 0, stream>>>(
            cur, Wl + (size_t)l * HIDDEN * HIDDEN, bl + (size_t)l * HIDDEN, oth);
        float* t = cur; cur = oth; oth = t;
    }

    pool_kernel<<<N_NODES / 4, 256, 0, stream>>>(cur, batch, pooledT, cnt);
    mean_kernel<<<(HIDDEN * NUM_GRAPHS) / 256, 256, 0, stream>>>(pooledT, cnt, meanT);
    final_kernel<<<(VOCAB + 255) / 256, 256, 0, stream>>>(meanT, Wout, bout, out);
}

// Round 2
// 1640.285 us; speedup vs baseline: 1.7135x; 1.7135x over previous
//
#include <hip/hip_runtime.h>

#define N_NODES 65536
#define N_EDGES 1048576
#define E_TOTAL (N_EDGES + N_NODES)
#define VOCAB 50000
#define HIDDEN 256
#define NUM_GRAPHS 64
#define NEG_SLOPE 0.2f
#define SM_EPS 1e-16f

// ---------------- gather: x = emb[nodes] ----------------
__global__ __launch_bounds__(256) void gather_kernel(const int* __restrict__ nodes,
    const float* __restrict__ emb, float* __restrict__ x) {
    int i = blockIdx.x;
    int t = threadIdx.x;
    x[(size_t)i * HIDDEN + t] = emb[(size_t)nodes[i] * HIDDEN + t];
}

// ---------------- CSR build (by dst) ----------------
__global__ __launch_bounds__(256) void hist_kernel(const int* __restrict__ ei, int* __restrict__ counts) {
    int e = blockIdx.x * 256 + threadIdx.x;
    if (e >= E_TOTAL) return;
    int dst = (e < N_EDGES) ? ei[N_EDGES + e] : (e - N_EDGES);
    atomicAdd(&counts[dst], 1);
}

__global__ __launch_bounds__(1024) void scan_kernel(const int* __restrict__ counts,
    int* __restrict__ row_ptr, int* __restrict__ cursor) {
    __shared__ int sp[1024];
    int t = threadIdx.x;
    int base = t * 64;
    int s = 0;
    for (int i = 0; i < 64; i++) s += counts[base + i];
    sp[t] = s;
    __syncthreads();
    for (int d = 1; d < 1024; d <<= 1) {
        int v = (t >= d) ? sp[t - d] : 0;
        __syncthreads();
        sp[t] += v;
        __syncthreads();
    }
    int run = sp[t] - s;
    for (int i = 0; i < 64; i++) {
        int c = counts[base + i];
        row_ptr[base + i] = run;
        cursor[base + i] = run;
        run += c;
    }
    if (t == 1023) row_ptr[N_NODES] = run;
}

__global__ __launch_bounds__(256) void scatter_kernel(const int* __restrict__ ei,
    int* __restrict__ cursor, int* __restrict__ src_sorted) {
    int e = blockIdx.x * 256 + threadIdx.x;
    if (e >= E_TOTAL) return;
    int src, dst;
    if (e < N_EDGES) { src = ei[e]; dst = ei[N_EDGES + e]; }
    else             { src = dst = e - N_EDGES; }
    int pos = atomicAdd(&cursor[dst], 1);
    src_sorted[pos] = src;
}

// ---------------- fp32 GEMM: C[N,256] = A[N,256] @ W[256,256] (+bias) ----------------
__global__ __launch_bounds__(256) void gemm_kernel(const float* __restrict__ A,
    const float* __restrict__ W, const float* __restrict__ bias,
    float* __restrict__ C) {
    __shared__ float As[16][64 + 4];
    __shared__ float Bs[16][128 + 8];
    int tid = threadIdx.x;
    int tx = tid & 15;
    int ty = tid >> 4;
    int m0 = blockIdx.x * 64;
    int n0 = blockIdx.y * 128;
    int arow = tid >> 2;
    int akc = (tid & 3) << 2;
    int brow = ty;
    int bcol = tx << 2;

    float acc0[4][4] = {{0.f}};
    float acc1[4][4] = {{0.f}};

    for (int k0 = 0; k0 < HIDDEN; k0 += 16) {
        float4 av  = *(const float4*)(A + (size_t)(m0 + arow) * HIDDEN + k0 + akc);
        float4 bv0 = *(const float4*)(W + (size_t)(k0 + brow) * HIDDEN + n0 + bcol);
        float4 bv1 = *(const float4*)(W + (size_t)(k0 + brow) * HIDDEN + n0 + 64 + bcol);
        __syncthreads();
        As[akc + 0][arow] = av.x;
        As[akc + 1][arow] = av.y;
        As[akc + 2][arow] = av.z;
        As[akc + 3][arow] = av.w;
        *(float4*)&Bs[brow][bcol] = bv0;
        *(float4*)&Bs[brow][64 + bcol] = bv1;
        __syncthreads();
        #pragma unroll
        for (int k = 0; k < 16; k++) {
            float4 a  = *(const float4*)&As[k][ty << 2];
            float4 b0 = *(const float4*)&Bs[k][tx << 2];
            float4 b1 = *(const float4*)&Bs[k][64 + (tx << 2)];
            float aa[4] = {a.x, a.y, a.z, a.w};
            float bb0[4] = {b0.x, b0.y, b0.z, b0.w};
            float bb1[4] = {b1.x, b1.y, b1.z, b1.w};
            #pragma unroll
            for (int i = 0; i < 4; i++) {
                #pragma unroll
                for (int j = 0; j < 4; j++) {
                    acc0[i][j] += aa[i] * bb0[j];
                    acc1[i][j] += aa[i] * bb1[j];
                }
            }
        }
    }
    #pragma unroll
    for (int i = 0; i < 4; i++) {
        int row = m0 + (ty << 2) + i;
        int c0 = n0 + (tx << 2);
        int c1 = n0 + 64 + (tx << 2);
        float4 r0 = make_float4(acc0[i][0], acc0[i][1], acc0[i][2], acc0[i][3]);
        float4 r1 = make_float4(acc1[i][0], acc1[i][1], acc1[i][2], acc1[i][3]);
        if (bias != nullptr) {
            r0.x += bias[c0 + 0]; r0.y += bias[c0 + 1]; r0.z += bias[c0 + 2]; r0.w += bias[c0 + 3];
            r1.x += bias[c1 + 0]; r1.y += bias[c1 + 1]; r1.z += bias[c1 + 2]; r1.w += bias[c1 + 3];
        }
        *(float4*)(C + (size_t)row * HIDDEN + c0) = r0;
        *(float4*)(C + (size_t)row * HIDDEN + c1) = r1;
    }
}

// ---------------- per-node attention scalars ----------------
__global__ __launch_bounds__(256) void dots_kernel(const float* __restrict__ h,
    const float* __restrict__ a_s, const float* __restrict__ a_d,
    float* __restrict__ es, float* __restrict__ ed) {
    int gtid = blockIdx.x * 256 + threadIdx.x;
    int node = gtid >> 6;
    int lane = threadIdx.x & 63;
    if (node >= N_NODES) return;
    float4 hv = *(const float4*)(h + (size_t)node * HIDDEN + lane * 4);
    float4 s4 = *(const float4*)(a_s + lane * 4);
    float4 d4 = *(const float4*)(a_d + lane * 4);
    float s = hv.x * s4.x + hv.y * s4.y + hv.z * s4.z + hv.w * s4.w;
    float d = hv.x * d4.x + hv.y * d4.y + hv.z * d4.z + hv.w * d4.w;
    for (int off = 32; off; off >>= 1) {
        s += __shfl_down(s, off);
        d += __shfl_down(d, off);
    }
    if (lane == 0) { es[node] = s; ed[node] = d; }
}

// ---------------- wave-per-dst segment softmax + weighted aggregate ----------------
__global__ __launch_bounds__(256) void agg_kernel(const float* __restrict__ h,
    const int* __restrict__ row_ptr, const int* __restrict__ src_sorted,
    const float* __restrict__ es, const float* __restrict__ ed,
    const float* __restrict__ bg, float* __restrict__ g) {
    int gtid = blockIdx.x * 256 + threadIdx.x;
    int dst = gtid >> 6;
    int lane = threadIdx.x & 63;
    if (dst >= N_NODES) return;
    int start = row_ptr[dst];
    int end = row_ptr[dst + 1];
    float edd = ed[dst];

    float m = -1e30f;
    for (int i = start + lane; i < end; i += 64) {
        float e = es[src_sorted[i]] + edd;
        e = (e > 0.f) ? e : NEG_SLOPE * e;
        m = fmaxf(m, e);
    }
    for (int off = 32; off; off >>= 1) m = fmaxf(m, __shfl_xor(m, off));

    float denom = 0.f;
    for (int i = start + lane; i < end; i += 64) {
        float e = es[src_sorted[i]] + edd;
        e = (e > 0.f) ? e : NEG_SLOPE * e;
        denom += __expf(e - m);
    }
    for (int off = 32; off; off >>= 1) denom += __shfl_xor(denom, off);
    float inv = 1.0f / (denom + SM_EPS);

    float4 acc = make_float4(0.f, 0.f, 0.f, 0.f);
    for (int i = start; i < end; i++) {
        int s = src_sorted[i];
        float e = es[s] + edd;
        e = (e > 0.f) ? e : NEG_SLOPE * e;
        float alpha = __expf(e - m) * inv;
        float4 hv = *(const float4*)(h + (size_t)s * HIDDEN + lane * 4);
        acc.x += alpha * hv.x;
        acc.y += alpha * hv.y;
        acc.z += alpha * hv.z;
        acc.w += alpha * hv.w;
    }
    float4 b4 = *(const float4*)(bg + lane * 4);
    acc.x = fmaxf(acc.x + b4.x, 0.f);
    acc.y = fmaxf(acc.y + b4.y, 0.f);
    acc.z = fmaxf(acc.z + b4.z, 0.f);
    acc.w = fmaxf(acc.w + b4.w, 0.f);
    *(float4*)(g + (size_t)dst * HIDDEN + lane * 4) = acc;
}

// ---------------- graph boundaries: batch is SORTED -> binary search ----------------
__global__ __launch_bounds__(128) void graph_bounds_kernel(const int* __restrict__ batch,
    int* __restrict__ gstart) {
    int g = threadIdx.x;
    if (g > NUM_GRAPHS) return;
    if (g == NUM_GRAPHS) { gstart[NUM_GRAPHS] = N_NODES; return; }
    // lower_bound: first i with batch[i] >= g
    int lo = 0, hi = N_NODES;
    while (lo < hi) {
        int mid = (lo + hi) >> 1;
        if (batch[mid] < g) lo = mid + 1; else hi = mid;
    }
    gstart[g] = lo;
}

// ---------------- mean pool: owner-computes partial reduction ----------------
// grid (NUM_GRAPHS, SPLITS); thread t owns column t; one atomicAdd per (block, col).
#define POOL_SPLITS 16
__global__ __launch_bounds__(256) void pool_partial_kernel(const float* __restrict__ x,
    const int* __restrict__ gstart, float* __restrict__ pooledT) {
    int g = blockIdx.x;
    int chunk = blockIdx.y;
    int t = threadIdx.x;
    int s = gstart[g];
    int e = gstart[g + 1];
    int n = e - s;
    int per = (n + POOL_SPLITS - 1) / POOL_SPLITS;
    int r0 = s + chunk * per;
    int r1 = min(r0 + per, e);
    if (r0 >= r1) return;
    float acc = 0.f;
    for (int r = r0; r < r1; r++) acc += x[(size_t)r * HIDDEN + t];
    atomicAdd(&pooledT[t * NUM_GRAPHS + g], acc);
}

__global__ __launch_bounds__(256) void mean_kernel(const float* __restrict__ pooledT,
    const int* __restrict__ gstart, float* __restrict__ meanT) {
    int i = blockIdx.x * 256 + threadIdx.x;  // HIDDEN*NUM_GRAPHS = 16384
    int g = i & (NUM_GRAPHS - 1);
    float c = (float)max(gstart[g + 1] - gstart[g], 1);
    meanT[i] = pooledT[i] / c;
}

// ---------------- final: out[64,50000] = pooled @ Wout + bout ----------------
__global__ __launch_bounds__(256) void final_kernel(const float* __restrict__ meanT,
    const float* __restrict__ Wout, const float* __restrict__ bout, float* __restrict__ out) {
    int j = blockIdx.x * 256 + threadIdx.x;
    if (j >= VOCAB) return;
    float acc[NUM_GRAPHS];
    #pragma unroll
    for (int g = 0; g < NUM_GRAPHS; g++) acc[g] = 0.f;
    for (int k = 0; k < HIDDEN; k++) {
        float w = Wout[(size_t)k * VOCAB + j];
        #pragma unroll
        for (int g = 0; g < NUM_GRAPHS; g++) acc[g] += meanT[k * NUM_GRAPHS + g] * w;
    }
    float b = bout[j];
    for (int g = 0; g < NUM_GRAPHS; g++) out[(size_t)g * VOCAB + j] = acc[g] + b;
}

extern "C" void kernel_launch(void* const* d_in, const int* in_sizes, int n_in,
                              void* d_out, int out_size, void* d_ws, size_t ws_size,
                              hipStream_t stream) {
    const int*   nodes = (const int*)d_in[0];
    const int*   ei    = (const int*)d_in[1];
    const int*   batch = (const int*)d_in[2];
    const float* emb   = (const float*)d_in[3];
    const float* Wg    = (const float*)d_in[4];
    const float* a_src = (const float*)d_in[5];
    const float* a_dst = (const float*)d_in[6];
    const float* bg    = (const float*)d_in[7];
    const float* Wl    = (const float*)d_in[8];
    const float* bl    = (const float*)d_in[9];
    const float* Wout  = (const float*)d_in[10];
    const float* bout  = (const float*)d_in[11];
    float* out = (float*)d_out;

    char* ws = (char*)d_ws;
    size_t off = 0;
    auto alloc = [&](size_t bytes) -> void* {
        void* p = ws + off;
        off += (bytes + 255) & ~(size_t)255;
        return p;
    };
    float* bufA       = (float*)alloc((size_t)N_NODES * HIDDEN * 4);
    float* bufB       = (float*)alloc((size_t)N_NODES * HIDDEN * 4);
    float* es         = (float*)alloc((size_t)N_NODES * 4);
    float* ed         = (float*)alloc((size_t)N_NODES * 4);
    int*   counts     = (int*)alloc((size_t)N_NODES * 4);
    int*   row_ptr    = (int*)alloc((size_t)(N_NODES + 1) * 4);
    int*   cursor     = (int*)alloc((size_t)N_NODES * 4);
    int*   src_sorted = (int*)alloc((size_t)E_TOTAL * 4);
    float* pooledT    = (float*)alloc((size_t)HIDDEN * NUM_GRAPHS * 4);
    float* meanT      = (float*)alloc((size_t)HIDDEN * NUM_GRAPHS * 4);
    int*   gstart     = (int*)alloc((size_t)(NUM_GRAPHS + 1) * 4);

    hipMemsetAsync(counts, 0, (size_t)N_NODES * 4, stream);
    hipMemsetAsync(pooledT, 0, (size_t)HIDDEN * NUM_GRAPHS * 4, stream);

    gather_kernel<<<N_NODES, 256, 0, stream>>>(nodes, emb, bufA);
    hist_kernel<<<(E_TOTAL + 255) / 256, 256, 0, stream>>>(ei, counts);
    scan_kernel<<<1, 1024, 0, stream>>>(counts, row_ptr, cursor);
    scatter_kernel<<<(E_TOTAL + 255) / 256, 256, 0, stream>>>(ei, cursor, src_sorted);

    float* cur = bufA;
    float* oth = bufB;
    for (int l = 0; l < 3; l++) {
        gemm_kernel<<<dim3(N_NODES / 64, HIDDEN / 128), 256, 0, stream>>>(
            cur, Wg + (size_t)l * HIDDEN * HIDDEN, nullptr, oth);
        dots_kernel<<<N_NODES / 4, 256, 0, stream>>>(
            oth, a_src + (size_t)l * HIDDEN, a_dst + (size_t)l * HIDDEN, es, ed);
        agg_kernel<<<N_NODES / 4, 256, 0, stream>>>(
            oth, row_ptr, src_sorted, es, ed, bg + (size_t)l * HIDDEN, cur);
        gemm_kernel<<<dim3(N_NODES / 64, HIDDEN / 128), 256, 0, stream>>>(
            cur, Wl + (size_t)l * HIDDEN * HIDDEN, bl + (size_t)l * HIDDEN, oth);
        float* t = cur; cur = oth; oth = t;
    }

    graph_bounds_kernel<<<1, 128, 0, stream>>>(batch, gstart);
    pool_partial_kernel<<<dim3(NUM_GRAPHS, POOL_SPLITS), 256, 0, stream>>>(cur, gstart, pooledT);
    mean_kernel<<<(HIDDEN * NUM_GRAPHS) / 256, 256, 0, stream>>>(pooledT, gstart, meanT);
    final_kernel<<<(VOCAB + 255) / 256, 256, 0, stream>>>(meanT, Wout, bout, out);
}

// Round 3
// 1048.430 us; speedup vs baseline: 2.6808x; 1.5645x over previous
//
#include <hip/hip_runtime.h>

#define N_NODES 65536
#define N_EDGES 1048576
#define E_TOTAL (N_EDGES + N_NODES)
#define VOCAB 50000
#define HIDDEN 256
#define NUM_GRAPHS 64
#define NEG_SLOPE 0.2f
#define SM_EPS 1e-16f

typedef _Float16 f16x8 __attribute__((ext_vector_type(8)));
typedef _Float16 f16x4 __attribute__((ext_vector_type(4)));
typedef float f32x4 __attribute__((ext_vector_type(4)));

// ---------------- gather: x = (fp16) emb[nodes] ----------------
__global__ __launch_bounds__(256) void gather_kernel(const int* __restrict__ nodes,
    const float* __restrict__ emb, _Float16* __restrict__ x) {
    int i = blockIdx.x;
    int t = threadIdx.x;
    x[(size_t)i * HIDDEN + t] = (_Float16)emb[(size_t)nodes[i] * HIDDEN + t];
}

// ---------------- weight transpose+convert: WT[mat][n][k] = (fp16) W[mat][k][n] ----------------
__global__ __launch_bounds__(256) void convert_wt_kernel(const float* __restrict__ Wg,
    const float* __restrict__ Wl, _Float16* __restrict__ WT) {
    int mat = blockIdx.y;
    int n = blockIdx.x;
    int k = threadIdx.x;
    const float* W = (mat < 3) ? (Wg + (size_t)mat * HIDDEN * HIDDEN)
                               : (Wl + (size_t)(mat - 3) * HIDDEN * HIDDEN);
    WT[(size_t)mat * HIDDEN * HIDDEN + (size_t)n * HIDDEN + k] = (_Float16)W[(size_t)k * HIDDEN + n];
}

// ---------------- CSR build (by dst) ----------------
__global__ __launch_bounds__(256) void hist_kernel(const int* __restrict__ ei, int* __restrict__ counts) {
    int e = blockIdx.x * 256 + threadIdx.x;
    if (e >= E_TOTAL) return;
    int dst = (e < N_EDGES) ? ei[N_EDGES + e] : (e - N_EDGES);
    atomicAdd(&counts[dst], 1);
}

__global__ __launch_bounds__(1024) void scan_kernel(const int* __restrict__ counts,
    int* __restrict__ row_ptr, int* __restrict__ cursor) {
    __shared__ int sp[1024];
    int t = threadIdx.x;
    int base = t * 64;
    int s = 0;
    for (int i = 0; i < 64; i++) s += counts[base + i];
    sp[t] = s;
    __syncthreads();
    for (int d = 1; d < 1024; d <<= 1) {
        int v = (t >= d) ? sp[t - d] : 0;
        __syncthreads();
        sp[t] += v;
        __syncthreads();
    }
    int run = sp[t] - s;
    for (int i = 0; i < 64; i++) {
        int c = counts[base + i];
        row_ptr[base + i] = run;
        cursor[base + i] = run;
        run += c;
    }
    if (t == 1023) row_ptr[N_NODES] = run;
}

__global__ __launch_bounds__(256) void scatter_kernel(const int* __restrict__ ei,
    int* __restrict__ cursor, int* __restrict__ src_sorted) {
    int e = blockIdx.x * 256 + threadIdx.x;
    if (e >= E_TOTAL) return;
    int src, dst;
    if (e < N_EDGES) { src = ei[e]; dst = ei[N_EDGES + e]; }
    else             { src = dst = e - N_EDGES; }
    int pos = atomicAdd(&cursor[dst], 1);
    src_sorted[pos] = src;
}

// ---------------- fp16 MFMA GEMM: C[M,256] = A[M,256] @ W  (WT[n][k] given) ----------------
// BM=128, BN=256 (full), BK=32; 256 threads = 4 waves; 16x16x32 MFMA.
// wave w owns rows w*32..w*32+31 (2 row-tiles) x all 16 col-tiles.
#define PAD_K 40
__global__ __launch_bounds__(256) void gemm_f16_kernel(const _Float16* __restrict__ A,
    const _Float16* __restrict__ WT, const float* __restrict__ bias,
    _Float16* __restrict__ C) {
    __shared__ _Float16 As[128][PAD_K];   // 10240 B
    __shared__ _Float16 Bs[256][PAD_K];   // 20480 B
    int tid = threadIdx.x;
    int wave = tid >> 6;
    int lane = tid & 63;
    int quad = lane >> 4;
    int l16 = lane & 15;
    int m0 = blockIdx.x * 128;

    f32x4 acc[2][16];
    #pragma unroll
    for (int rt = 0; rt < 2; rt++)
        #pragma unroll
        for (int ct = 0; ct < 16; ct++)
            acc[rt][ct] = (f32x4){0.f, 0.f, 0.f, 0.f};

    for (int k0 = 0; k0 < HIDDEN; k0 += 32) {
        __syncthreads();
        // stage A: 128 rows x 32 halfs = 512 16B-chunks; 2 per thread
        #pragma unroll
        for (int i = 0; i < 2; i++) {
            int c = tid + i * 256;
            int row = c >> 2, q = c & 3;
            *(f16x8*)&As[row][q * 8] =
                *(const f16x8*)(A + (size_t)(m0 + row) * HIDDEN + k0 + q * 8);
        }
        // stage B: 256 rows x 32 halfs = 1024 chunks; 4 per thread
        #pragma unroll
        for (int i = 0; i < 4; i++) {
            int c = tid + i * 256;
            int row = c >> 2, q = c & 3;
            *(f16x8*)&Bs[row][q * 8] =
                *(const f16x8*)(WT + (size_t)row * HIDDEN + k0 + q * 8);
        }
        __syncthreads();
        f16x8 a0 = *(const f16x8*)&As[wave * 32 + l16][quad * 8];
        f16x8 a1 = *(const f16x8*)&As[wave * 32 + 16 + l16][quad * 8];
        #pragma unroll
        for (int ct = 0; ct < 16; ct++) {
            f16x8 b = *(const f16x8*)&Bs[ct * 16 + l16][quad * 8];
            acc[0][ct] = __builtin_amdgcn_mfma_f32_16x16x32_f16(a0, b, acc[0][ct], 0, 0, 0);
            acc[1][ct] = __builtin_amdgcn_mfma_f32_16x16x32_f16(a1, b, acc[1][ct], 0, 0, 0);
        }
    }
    // epilogue: C/D layout col=lane&15, row=quad*4+reg
    #pragma unroll
    for (int rt = 0; rt < 2; rt++) {
        #pragma unroll
        for (int ct = 0; ct < 16; ct++) {
            int col = ct * 16 + l16;
            float bv = (bias != nullptr) ? bias[col] : 0.f;
            int rowbase = m0 + wave * 32 + rt * 16 + quad * 4;
            #pragma unroll
            for (int r = 0; r < 4; r++) {
                C[(size_t)(rowbase + r) * HIDDEN + col] = (_Float16)(acc[rt][ct][r] + bv);
            }
        }
    }
}

// ---------------- per-node attention scalars (h fp16 -> es/ed fp32) ----------------
__global__ __launch_bounds__(256) void dots_kernel(const _Float16* __restrict__ h,
    const float* __restrict__ a_s, const float* __restrict__ a_d,
    float* __restrict__ es, float* __restrict__ ed) {
    int gtid = blockIdx.x * 256 + threadIdx.x;
    int node = gtid >> 6;
    int lane = threadIdx.x & 63;
    if (node >= N_NODES) return;
    f16x4 hv4 = *(const f16x4*)(h + (size_t)node * HIDDEN + lane * 4);
    float4 s4 = *(const float4*)(a_s + lane * 4);
    float4 d4 = *(const float4*)(a_d + lane * 4);
    float h0 = (float)hv4[0], h1 = (float)hv4[1], h2 = (float)hv4[2], h3 = (float)hv4[3];
    float s = h0 * s4.x + h1 * s4.y + h2 * s4.z + h3 * s4.w;
    float d = h0 * d4.x + h1 * d4.y + h2 * d4.z + h3 * d4.w;
    for (int off = 32; off; off >>= 1) {
        s += __shfl_down(s, off);
        d += __shfl_down(d, off);
    }
    if (lane == 0) { es[node] = s; ed[node] = d; }
}

// ---------------- wave-per-dst segment softmax + weighted aggregate (fp16 h) ----------------
__global__ __launch_bounds__(256) void agg_kernel(const _Float16* __restrict__ h,
    const int* __restrict__ row_ptr, const int* __restrict__ src_sorted,
    const float* __restrict__ es, const float* __restrict__ ed,
    const float* __restrict__ bg, float* __restrict__ wbuf, _Float16* __restrict__ g) {
    int gtid = blockIdx.x * 256 + threadIdx.x;
    int dst = gtid >> 6;
    int lane = threadIdx.x & 63;
    if (dst >= N_NODES) return;
    int start = row_ptr[dst];
    int end = row_ptr[dst + 1];
    float edd = ed[dst];

    // pass 1a: segment max
    float m = -1e30f;
    for (int i = start + lane; i < end; i += 64) {
        float e = es[src_sorted[i]] + edd;
        e = (e > 0.f) ? e : NEG_SLOPE * e;
        m = fmaxf(m, e);
    }
    for (int off = 32; off; off >>= 1) m = fmaxf(m, __shfl_xor(m, off));

    // pass 1b: w_i = exp(e-m), write to wbuf; denom
    float denom = 0.f;
    for (int i = start + lane; i < end; i += 64) {
        float e = es[src_sorted[i]] + edd;
        e = (e > 0.f) ? e : NEG_SLOPE * e;
        float w = __expf(e - m);
        wbuf[i] = w;
        denom += w;
    }
    for (int off = 32; off; off >>= 1) denom += __shfl_xor(denom, off);
    float inv = 1.0f / (denom + SM_EPS);

    // pass 2: weighted accumulate, unroll x2; lane owns 4 contiguous columns
    float4 acc = make_float4(0.f, 0.f, 0.f, 0.f);
    int i = start;
    for (; i + 1 < end; i += 2) {
        int s0 = src_sorted[i];
        int s1 = src_sorted[i + 1];
        float a0 = wbuf[i] * inv;
        float a1 = wbuf[i + 1] * inv;
        f16x4 r0 = *(const f16x4*)(h + (size_t)s0 * HIDDEN + lane * 4);
        f16x4 r1 = *(const f16x4*)(h + (size_t)s1 * HIDDEN + lane * 4);
        acc.x += a0 * (float)r0[0] + a1 * (float)r1[0];
        acc.y += a0 * (float)r0[1] + a1 * (float)r1[1];
        acc.z += a0 * (float)r0[2] + a1 * (float)r1[2];
        acc.w += a0 * (float)r0[3] + a1 * (float)r1[3];
    }
    if (i < end) {
        int s0 = src_sorted[i];
        float a0 = wbuf[i] * inv;
        f16x4 r0 = *(const f16x4*)(h + (size_t)s0 * HIDDEN + lane * 4);
        acc.x += a0 * (float)r0[0];
        acc.y += a0 * (float)r0[1];
        acc.z += a0 * (float)r0[2];
        acc.w += a0 * (float)r0[3];
    }
    float4 b4 = *(const float4*)(bg + lane * 4);
    f16x4 outv;
    outv[0] = (_Float16)fmaxf(acc.x + b4.x, 0.f);
    outv[1] = (_Float16)fmaxf(acc.y + b4.y, 0.f);
    outv[2] = (_Float16)fmaxf(acc.z + b4.z, 0.f);
    outv[3] = (_Float16)fmaxf(acc.w + b4.w, 0.f);
    *(f16x4*)(g + (size_t)dst * HIDDEN + lane * 4) = outv;
}

// ---------------- graph boundaries: batch is SORTED -> binary search ----------------
__global__ __launch_bounds__(128) void graph_bounds_kernel(const int* __restrict__ batch,
    int* __restrict__ gstart) {
    int g = threadIdx.x;
    if (g > NUM_GRAPHS) return;
    if (g == NUM_GRAPHS) { gstart[NUM_GRAPHS] = N_NODES; return; }
    int lo = 0, hi = N_NODES;
    while (lo < hi) {
        int mid = (lo + hi) >> 1;
        if (batch[mid] < g) lo = mid + 1; else hi = mid;
    }
    gstart[g] = lo;
}

// ---------------- mean pool: owner-computes partial reduction (fp16 x) ----------------
#define POOL_SPLITS 16
__global__ __launch_bounds__(256) void pool_partial_kernel(const _Float16* __restrict__ x,
    const int* __restrict__ gstart, float* __restrict__ pooledT) {
    int g = blockIdx.x;
    int chunk = blockIdx.y;
    int t = threadIdx.x;
    int s = gstart[g];
    int e = gstart[g + 1];
    int n = e - s;
    int per = (n + POOL_SPLITS - 1) / POOL_SPLITS;
    int r0 = s + chunk * per;
    int r1 = min(r0 + per, e);
    if (r0 >= r1) return;
    float acc = 0.f;
    for (int r = r0; r < r1; r++) acc += (float)x[(size_t)r * HIDDEN + t];
    atomicAdd(&pooledT[t * NUM_GRAPHS + g], acc);
}

__global__ __launch_bounds__(256) void mean_kernel(const float* __restrict__ pooledT,
    const int* __restrict__ gstart, float* __restrict__ meanT) {
    int i = blockIdx.x * 256 + threadIdx.x;
    int g = i & (NUM_GRAPHS - 1);
    float c = (float)max(gstart[g + 1] - gstart[g], 1);
    meanT[i] = pooledT[i] / c;
}

// ---------------- final: out[64,50000] = pooled @ Wout + bout (fp32) ----------------
__global__ __launch_bounds__(256) void final_kernel(const float* __restrict__ meanT,
    const float* __restrict__ Wout, const float* __restrict__ bout, float* __restrict__ out) {
    int j = blockIdx.x * 256 + threadIdx.x;
    if (j >= VOCAB) return;
    float acc[NUM_GRAPHS];
    #pragma unroll
    for (int g = 0; g < NUM_GRAPHS; g++) acc[g] = 0.f;
    for (int k = 0; k < HIDDEN; k++) {
        float w = Wout[(size_t)k * VOCAB + j];
        #pragma unroll
        for (int g = 0; g < NUM_GRAPHS; g++) acc[g] += meanT[k * NUM_GRAPHS + g] * w;
    }
    float b = bout[j];
    for (int g = 0; g < NUM_GRAPHS; g++) out[(size_t)g * VOCAB + j] = acc[g] + b;
}

extern "C" void kernel_launch(void* const* d_in, const int* in_sizes, int n_in,
                              void* d_out, int out_size, void* d_ws, size_t ws_size,
                              hipStream_t stream) {
    const int*   nodes = (const int*)d_in[0];
    const int*   ei    = (const int*)d_in[1];
    const int*   batch = (const int*)d_in[2];
    const float* emb   = (const float*)d_in[3];
    const float* Wg    = (const float*)d_in[4];
    const float* a_src = (const float*)d_in[5];
    const float* a_dst = (const float*)d_in[6];
    const float* bg    = (const float*)d_in[7];
    const float* Wl    = (const float*)d_in[8];
    const float* bl    = (const float*)d_in[9];
    const float* Wout  = (const float*)d_in[10];
    const float* bout  = (const float*)d_in[11];
    float* out = (float*)d_out;

    char* ws = (char*)d_ws;
    size_t off = 0;
    auto alloc = [&](size_t bytes) -> void* {
        void* p = ws + off;
        off += (bytes + 255) & ~(size_t)255;
        return p;
    };
    _Float16* bufA    = (_Float16*)alloc((size_t)N_NODES * HIDDEN * 2);
    _Float16* bufB    = (_Float16*)alloc((size_t)N_NODES * HIDDEN * 2);
    _Float16* WT      = (_Float16*)alloc((size_t)6 * HIDDEN * HIDDEN * 2);
    float* es         = (float*)alloc((size_t)N_NODES * 4);
    float* ed         = (float*)alloc((size_t)N_NODES * 4);
    int*   counts     = (int*)alloc((size_t)N_NODES * 4);
    int*   row_ptr    = (int*)alloc((size_t)(N_NODES + 1) * 4);
    int*   cursor     = (int*)alloc((size_t)N_NODES * 4);
    int*   src_sorted = (int*)alloc((size_t)E_TOTAL * 4);
    float* wbuf       = (float*)alloc((size_t)E_TOTAL * 4);
    float* pooledT    = (float*)alloc((size_t)HIDDEN * NUM_GRAPHS * 4);
    float* meanT      = (float*)alloc((size_t)HIDDEN * NUM_GRAPHS * 4);
    int*   gstart     = (int*)alloc((size_t)(NUM_GRAPHS + 1) * 4);

    hipMemsetAsync(counts, 0, (size_t)N_NODES * 4, stream);
    hipMemsetAsync(pooledT, 0, (size_t)HIDDEN * NUM_GRAPHS * 4, stream);

    convert_wt_kernel<<<dim3(HIDDEN, 6), 256, 0, stream>>>(Wg, Wl, WT);
    gather_kernel<<<N_NODES, 256, 0, stream>>>(nodes, emb, bufA);
    hist_kernel<<<(E_TOTAL + 255) / 256, 256, 0, stream>>>(ei, counts);
    scan_kernel<<<1, 1024, 0, stream>>>(counts, row_ptr, cursor);
    scatter_kernel<<<(E_TOTAL + 255) / 256, 256, 0, stream>>>(ei, cursor, src_sorted);

    _Float16* cur = bufA;
    _Float16* oth = bufB;
    for (int l = 0; l < 3; l++) {
        gemm_f16_kernel<<<N_NODES / 128, 256, 0, stream>>>(
            cur, WT + (size_t)l * HIDDEN * HIDDEN, nullptr, oth);
        dots_kernel<<<N_NODES / 4, 256, 0, stream>>>(
            oth, a_src + (size_t)l * HIDDEN, a_dst + (size_t)l * HIDDEN, es, ed);
        agg_kernel<<<N_NODES / 4, 256, 0, stream>>>(
            oth, row_ptr, src_sorted, es, ed, bg + (size_t)l * HIDDEN, wbuf, cur);
        gemm_f16_kernel<<<N_NODES / 128, 256, 0, stream>>>(
            cur, WT + (size_t)(3 + l) * HIDDEN * HIDDEN, bl + (size_t)l * HIDDEN, oth);
        _Float16* t = cur; cur = oth; oth = t;
    }

    graph_bounds_kernel<<<1, 128, 0, stream>>>(batch, gstart);
    pool_partial_kernel<<<dim3(NUM_GRAPHS, POOL_SPLITS), 256, 0, stream>>>(cur, gstart, pooledT);
    mean_kernel<<<(HIDDEN * NUM_GRAPHS) / 256, 256, 0, stream>>>(pooledT, gstart, meanT);
    final_kernel<<<(VOCAB + 255) / 256, 256, 0, stream>>>(meanT, Wout, bout, out);
}

// Round 4
// 969.403 us; speedup vs baseline: 2.8993x; 1.0815x over previous
//
#include <hip/hip_runtime.h>

#define N_NODES 65536
#define N_EDGES 1048576
#define E_TOTAL (N_EDGES + N_NODES)
#define VOCAB 50000
#define HIDDEN 256
#define NUM_GRAPHS 64
#define NEG_SLOPE 0.2f
#define SM_EPS 1e-16f

typedef _Float16 f16x8 __attribute__((ext_vector_type(8)));
typedef _Float16 f16x4 __attribute__((ext_vector_type(4)));
typedef float f32x4 __attribute__((ext_vector_type(4)));

// ---------------- gather: x = (fp16) emb[nodes] ----------------
__global__ __launch_bounds__(256) void gather_kernel(const int* __restrict__ nodes,
    const float* __restrict__ emb, _Float16* __restrict__ x) {
    int i = blockIdx.x;
    int t = threadIdx.x;
    x[(size_t)i * HIDDEN + t] = (_Float16)emb[(size_t)nodes[i] * HIDDEN + t];
}

// ---------------- weight transpose+convert: WT[mat][n][k] = (fp16) W[mat][k][n] ----------------
__global__ __launch_bounds__(256) void convert_wt_kernel(const float* __restrict__ Wg,
    const float* __restrict__ Wl, _Float16* __restrict__ WT) {
    int mat = blockIdx.y;
    int n = blockIdx.x;
    int k = threadIdx.x;
    const float* W = (mat < 3) ? (Wg + (size_t)mat * HIDDEN * HIDDEN)
                               : (Wl + (size_t)(mat - 3) * HIDDEN * HIDDEN);
    WT[(size_t)mat * HIDDEN * HIDDEN + (size_t)n * HIDDEN + k] = (_Float16)W[(size_t)k * HIDDEN + n];
}

// ---------------- CSR build (by dst) ----------------
__global__ __launch_bounds__(256) void hist_kernel(const int* __restrict__ ei, int* __restrict__ counts) {
    int e = blockIdx.x * 256 + threadIdx.x;
    if (e >= E_TOTAL) return;
    int dst = (e < N_EDGES) ? ei[N_EDGES + e] : (e - N_EDGES);
    atomicAdd(&counts[dst], 1);
}

__global__ __launch_bounds__(1024) void scan_kernel(const int* __restrict__ counts,
    int* __restrict__ row_ptr, int* __restrict__ cursor) {
    __shared__ int sp[1024];
    int t = threadIdx.x;
    int base = t * 64;
    int s = 0;
    for (int i = 0; i < 64; i++) s += counts[base + i];
    sp[t] = s;
    __syncthreads();
    for (int d = 1; d < 1024; d <<= 1) {
        int v = (t >= d) ? sp[t - d] : 0;
        __syncthreads();
        sp[t] += v;
        __syncthreads();
    }
    int run = sp[t] - s;
    for (int i = 0; i < 64; i++) {
        int c = counts[base + i];
        row_ptr[base + i] = run;
        cursor[base + i] = run;
        run += c;
    }
    if (t == 1023) row_ptr[N_NODES] = run;
}

__global__ __launch_bounds__(256) void scatter_kernel(const int* __restrict__ ei,
    int* __restrict__ cursor, int* __restrict__ src_sorted) {
    int e = blockIdx.x * 256 + threadIdx.x;
    if (e >= E_TOTAL) return;
    int src, dst;
    if (e < N_EDGES) { src = ei[e]; dst = ei[N_EDGES + e]; }
    else             { src = dst = e - N_EDGES; }
    int pos = atomicAdd(&cursor[dst], 1);
    src_sorted[pos] = src;
}

// ---------------- fp16 MFMA GEMM: C[M,256] = A[M,256] @ W  (WT[n][k] given) ----------------
#define PAD_K 40
__global__ __launch_bounds__(256) void gemm_f16_kernel(const _Float16* __restrict__ A,
    const _Float16* __restrict__ WT, const float* __restrict__ bias,
    _Float16* __restrict__ C) {
    __shared__ _Float16 As[128][PAD_K];
    __shared__ _Float16 Bs[256][PAD_K];
    int tid = threadIdx.x;
    int wave = tid >> 6;
    int lane = tid & 63;
    int quad = lane >> 4;
    int l16 = lane & 15;
    int m0 = blockIdx.x * 128;

    f32x4 acc[2][16];
    #pragma unroll
    for (int rt = 0; rt < 2; rt++)
        #pragma unroll
        for (int ct = 0; ct < 16; ct++)
            acc[rt][ct] = (f32x4){0.f, 0.f, 0.f, 0.f};

    for (int k0 = 0; k0 < HIDDEN; k0 += 32) {
        __syncthreads();
        #pragma unroll
        for (int i = 0; i < 2; i++) {
            int c = tid + i * 256;
            int row = c >> 2, q = c & 3;
            *(f16x8*)&As[row][q * 8] =
                *(const f16x8*)(A + (size_t)(m0 + row) * HIDDEN + k0 + q * 8);
        }
        #pragma unroll
        for (int i = 0; i < 4; i++) {
            int c = tid + i * 256;
            int row = c >> 2, q = c & 3;
            *(f16x8*)&Bs[row][q * 8] =
                *(const f16x8*)(WT + (size_t)row * HIDDEN + k0 + q * 8);
        }
        __syncthreads();
        f16x8 a0 = *(const f16x8*)&As[wave * 32 + l16][quad * 8];
        f16x8 a1 = *(const f16x8*)&As[wave * 32 + 16 + l16][quad * 8];
        #pragma unroll
        for (int ct = 0; ct < 16; ct++) {
            f16x8 b = *(const f16x8*)&Bs[ct * 16 + l16][quad * 8];
            acc[0][ct] = __builtin_amdgcn_mfma_f32_16x16x32_f16(a0, b, acc[0][ct], 0, 0, 0);
            acc[1][ct] = __builtin_amdgcn_mfma_f32_16x16x32_f16(a1, b, acc[1][ct], 0, 0, 0);
        }
    }
    #pragma unroll
    for (int rt = 0; rt < 2; rt++) {
        #pragma unroll
        for (int ct = 0; ct < 16; ct++) {
            int col = ct * 16 + l16;
            float bv = (bias != nullptr) ? bias[col] : 0.f;
            int rowbase = m0 + wave * 32 + rt * 16 + quad * 4;
            #pragma unroll
            for (int r = 0; r < 4; r++) {
                C[(size_t)(rowbase + r) * HIDDEN + col] = (_Float16)(acc[rt][ct][r] + bv);
            }
        }
    }
}

// ---------------- per-node attention scalars (h fp16 -> es/ed fp32) ----------------
__global__ __launch_bounds__(256) void dots_kernel(const _Float16* __restrict__ h,
    const float* __restrict__ a_s, const float* __restrict__ a_d,
    float* __restrict__ es, float* __restrict__ ed) {
    int gtid = blockIdx.x * 256 + threadIdx.x;
    int node = gtid >> 6;
    int lane = threadIdx.x & 63;
    if (node >= N_NODES) return;
    f16x4 hv4 = *(const f16x4*)(h + (size_t)node * HIDDEN + lane * 4);
    float4 s4 = *(const float4*)(a_s + lane * 4);
    float4 d4 = *(const float4*)(a_d + lane * 4);
    float h0 = (float)hv4[0], h1 = (float)hv4[1], h2 = (float)hv4[2], h3 = (float)hv4[3];
    float s = h0 * s4.x + h1 * s4.y + h2 * s4.z + h3 * s4.w;
    float d = h0 * d4.x + h1 * d4.y + h2 * d4.z + h3 * d4.w;
    for (int off = 32; off; off >>= 1) {
        s += __shfl_down(s, off);
        d += __shfl_down(d, off);
    }
    if (lane == 0) { es[node] = s; ed[node] = d; }
}

// ---------------- wave-per-dst segment softmax + weighted aggregate (fp16 h) ----------------
__global__ __launch_bounds__(256) void agg_kernel(const _Float16* __restrict__ h,
    const int* __restrict__ row_ptr, const int* __restrict__ src_sorted,
    const float* __restrict__ es, const float* __restrict__ ed,
    const float* __restrict__ bg, float* __restrict__ wbuf, _Float16* __restrict__ g) {
    int gtid = blockIdx.x * 256 + threadIdx.x;
    int dst = gtid >> 6;
    int lane = threadIdx.x & 63;
    if (dst >= N_NODES) return;
    int start = row_ptr[dst];
    int end = row_ptr[dst + 1];
    float edd = ed[dst];

    float m = -1e30f;
    for (int i = start + lane; i < end; i += 64) {
        float e = es[src_sorted[i]] + edd;
        e = (e > 0.f) ? e : NEG_SLOPE * e;
        m = fmaxf(m, e);
    }
    for (int off = 32; off; off >>= 1) m = fmaxf(m, __shfl_xor(m, off));

    float denom = 0.f;
    for (int i = start + lane; i < end; i += 64) {
        float e = es[src_sorted[i]] + edd;
        e = (e > 0.f) ? e : NEG_SLOPE * e;
        float w = __expf(e - m);
        wbuf[i] = w;
        denom += w;
    }
    for (int off = 32; off; off >>= 1) denom += __shfl_xor(denom, off);
    float inv = 1.0f / (denom + SM_EPS);

    float4 acc = make_float4(0.f, 0.f, 0.f, 0.f);
    int i = start;
    for (; i + 1 < end; i += 2) {
        int s0 = src_sorted[i];
        int s1 = src_sorted[i + 1];
        float a0 = wbuf[i] * inv;
        float a1 = wbuf[i + 1] * inv;
        f16x4 r0 = *(const f16x4*)(h + (size_t)s0 * HIDDEN + lane * 4);
        f16x4 r1 = *(const f16x4*)(h + (size_t)s1 * HIDDEN + lane * 4);
        acc.x += a0 * (float)r0[0] + a1 * (float)r1[0];
        acc.y += a0 * (float)r0[1] + a1 * (float)r1[1];
        acc.z += a0 * (float)r0[2] + a1 * (float)r1[2];
        acc.w += a0 * (float)r0[3] + a1 * (float)r1[3];
    }
    if (i < end) {
        int s0 = src_sorted[i];
        float a0 = wbuf[i] * inv;
        f16x4 r0 = *(const f16x4*)(h + (size_t)s0 * HIDDEN + lane * 4);
        acc.x += a0 * (float)r0[0];
        acc.y += a0 * (float)r0[1];
        acc.z += a0 * (float)r0[2];
        acc.w += a0 * (float)r0[3];
    }
    float4 b4 = *(const float4*)(bg + lane * 4);
    f16x4 outv;
    outv[0] = (_Float16)fmaxf(acc.x + b4.x, 0.f);
    outv[1] = (_Float16)fmaxf(acc.y + b4.y, 0.f);
    outv[2] = (_Float16)fmaxf(acc.z + b4.z, 0.f);
    outv[3] = (_Float16)fmaxf(acc.w + b4.w, 0.f);
    *(f16x4*)(g + (size_t)dst * HIDDEN + lane * 4) = outv;
}

// ---------------- graph boundaries: batch is SORTED -> binary search ----------------
__global__ __launch_bounds__(128) void graph_bounds_kernel(const int* __restrict__ batch,
    int* __restrict__ gstart) {
    int g = threadIdx.x;
    if (g > NUM_GRAPHS) return;
    if (g == NUM_GRAPHS) { gstart[NUM_GRAPHS] = N_NODES; return; }
    int lo = 0, hi = N_NODES;
    while (lo < hi) {
        int mid = (lo + hi) >> 1;
        if (batch[mid] < g) lo = mid + 1; else hi = mid;
    }
    gstart[g] = lo;
}

// ---------------- mean pool: owner-computes partial reduction (fp16 x) ----------------
#define POOL_SPLITS 16
__global__ __launch_bounds__(256) void pool_partial_kernel(const _Float16* __restrict__ x,
    const int* __restrict__ gstart, float* __restrict__ pooledT) {
    int g = blockIdx.x;
    int chunk = blockIdx.y;
    int t = threadIdx.x;
    int s = gstart[g];
    int e = gstart[g + 1];
    int n = e - s;
    int per = (n + POOL_SPLITS - 1) / POOL_SPLITS;
    int r0 = s + chunk * per;
    int r1 = min(r0 + per, e);
    if (r0 >= r1) return;
    float acc = 0.f;
    for (int r = r0; r < r1; r++) acc += (float)x[(size_t)r * HIDDEN + t];
    atomicAdd(&pooledT[t * NUM_GRAPHS + g], acc);
}

__global__ __launch_bounds__(256) void mean_kernel(const float* __restrict__ pooledT,
    const int* __restrict__ gstart, float* __restrict__ meanT) {
    int i = blockIdx.x * 256 + threadIdx.x;
    int g = i & (NUM_GRAPHS - 1);
    float c = (float)max(gstart[g + 1] - gstart[g], 1);
    meanT[i] = pooledT[i] / c;
}

// ---------------- final: out[64,50000] = pooled @ Wout + bout (fp32) ----------------
// Grid (196, 4): thread owns one vocab column x 16 graphs. 4x wave count vs
// the 1-y version (12 waves/CU), 16-reg accumulator, unroll-4 k-loop for
// outstanding loads. Extra Wout reads come from L3 (Wout is L3-resident).
#define FINAL_GSPLIT 4
#define G_PER (NUM_GRAPHS / FINAL_GSPLIT)
__global__ __launch_bounds__(256) void final_kernel(const float* __restrict__ meanT,
    const float* __restrict__ Wout, const float* __restrict__ bout, float* __restrict__ out) {
    int j = blockIdx.x * 256 + threadIdx.x;
    int g0 = blockIdx.y * G_PER;
    if (j >= VOCAB) return;
    float acc[G_PER];
    #pragma unroll
    for (int g = 0; g < G_PER; g++) acc[g] = 0.f;
    #pragma unroll 4
    for (int k = 0; k < HIDDEN; k++) {
        float w = Wout[(size_t)k * VOCAB + j];
        #pragma unroll
        for (int g = 0; g < G_PER; g++) acc[g] += meanT[k * NUM_GRAPHS + g0 + g] * w;
    }
    float b = bout[j];
    #pragma unroll
    for (int g = 0; g < G_PER; g++) out[(size_t)(g0 + g) * VOCAB + j] = acc[g] + b;
}

extern "C" void kernel_launch(void* const* d_in, const int* in_sizes, int n_in,
                              void* d_out, int out_size, void* d_ws, size_t ws_size,
                              hipStream_t stream) {
    const int*   nodes = (const int*)d_in[0];
    const int*   ei    = (const int*)d_in[1];
    const int*   batch = (const int*)d_in[2];
    const float* emb   = (const float*)d_in[3];
    const float* Wg    = (const float*)d_in[4];
    const float* a_src = (const float*)d_in[5];
    const float* a_dst = (const float*)d_in[6];
    const float* bg    = (const float*)d_in[7];
    const float* Wl    = (const float*)d_in[8];
    const float* bl    = (const float*)d_in[9];
    const float* Wout  = (const float*)d_in[10];
    const float* bout  = (const float*)d_in[11];
    float* out = (float*)d_out;

    char* ws = (char*)d_ws;
    size_t off = 0;
    auto alloc = [&](size_t bytes) -> void* {
        void* p = ws + off;
        off += (bytes + 255) & ~(size_t)255;
        return p;
    };
    _Float16* bufA    = (_Float16*)alloc((size_t)N_NODES * HIDDEN * 2);
    _Float16* bufB    = (_Float16*)alloc((size_t)N_NODES * HIDDEN * 2);
    _Float16* WT      = (_Float16*)alloc((size_t)6 * HIDDEN * HIDDEN * 2);
    float* es         = (float*)alloc((size_t)N_NODES * 4);
    float* ed         = (float*)alloc((size_t)N_NODES * 4);
    int*   counts     = (int*)alloc((size_t)N_NODES * 4);
    int*   row_ptr    = (int*)alloc((size_t)(N_NODES + 1) * 4);
    int*   cursor     = (int*)alloc((size_t)N_NODES * 4);
    int*   src_sorted = (int*)alloc((size_t)E_TOTAL * 4);
    float* wbuf       = (float*)alloc((size_t)E_TOTAL * 4);
    float* pooledT    = (float*)alloc((size_t)HIDDEN * NUM_GRAPHS * 4);
    float* meanT      = (float*)alloc((size_t)HIDDEN * NUM_GRAPHS * 4);
    int*   gstart     = (int*)alloc((size_t)(NUM_GRAPHS + 1) * 4);

    hipMemsetAsync(counts, 0, (size_t)N_NODES * 4, stream);
    hipMemsetAsync(pooledT, 0, (size_t)HIDDEN * NUM_GRAPHS * 4, stream);

    convert_wt_kernel<<<dim3(HIDDEN, 6), 256, 0, stream>>>(Wg, Wl, WT);
    gather_kernel<<<N_NODES, 256, 0, stream>>>(nodes, emb, bufA);
    hist_kernel<<<(E_TOTAL + 255) / 256, 256, 0, stream>>>(ei, counts);
    scan_kernel<<<1, 1024, 0, stream>>>(counts, row_ptr, cursor);
    scatter_kernel<<<(E_TOTAL + 255) / 256, 256, 0, stream>>>(ei, cursor, src_sorted);

    _Float16* cur = bufA;
    _Float16* oth = bufB;
    for (int l = 0; l < 3; l++) {
        gemm_f16_kernel<<<N_NODES / 128, 256, 0, stream>>>(
            cur, WT + (size_t)l * HIDDEN * HIDDEN, nullptr, oth);
        dots_kernel<<<N_NODES / 4, 256, 0, stream>>>(
            oth, a_src + (size_t)l * HIDDEN, a_dst + (size_t)l * HIDDEN, es, ed);
        agg_kernel<<<N_NODES / 4, 256, 0, stream>>>(
            oth, row_ptr, src_sorted, es, ed, bg + (size_t)l * HIDDEN, wbuf, cur);
        gemm_f16_kernel<<<N_NODES / 128, 256, 0, stream>>>(
            cur, WT + (size_t)(3 + l) * HIDDEN * HIDDEN, bl + (size_t)l * HIDDEN, oth);
        _Float16* t = cur; cur = oth; oth = t;
    }

    graph_bounds_kernel<<<1, 128, 0, stream>>>(batch, gstart);
    pool_partial_kernel<<<dim3(NUM_GRAPHS, POOL_SPLITS), 256, 0, stream>>>(cur, gstart, pooledT);
    mean_kernel<<<(HIDDEN * NUM_GRAPHS) / 256, 256, 0, stream>>>(pooledT, gstart, meanT);
    final_kernel<<<dim3((VOCAB + 255) / 256, FINAL_GSPLIT), 256, 0, stream>>>(meanT, Wout, bout, out);
}